// Round 11
// baseline (253.957 us; speedup 1.0000x reference)
//
#include <hip/hip_runtime.h>
#include <hip/hip_bf16.h>

typedef __bf16 bf16x8 __attribute__((ext_vector_type(8)));
typedef float f32x4 __attribute__((ext_vector_type(4)));
typedef float f32x4u __attribute__((ext_vector_type(4), aligned(4)));
typedef unsigned short u16x8 __attribute__((ext_vector_type(8)));

typedef __attribute__((address_space(1))) const unsigned int gu32;
typedef __attribute__((address_space(3))) unsigned int lu32;

#define B_SZ   1024
#define IN_SZ  512
#define HID    128
#define OUT_SZ 64
#define BK     32
#define NKT    16        // K main loop = 512
#define M2     65536     // 128 h x 512 i   (main GEMM M, power of 2)

static __device__ __forceinline__ unsigned short f2bf(float f) {
    __hip_bfloat16 h = __float2bfloat16(f);
    return *reinterpret_cast<unsigned short*>(&h);
}

// ---------------- prep: t_hat bf16 [1024][512], tc, xhT [513][1024] --------
__global__ __launch_bounds__(256) void prep_kernel(
    const float* __restrict__ img, const float* __restrict__ tab,
    unsigned short* __restrict__ tbt, float* __restrict__ xhT,
    float* __restrict__ tc)
{
    const int blk = blockIdx.x;   // 0..1023
    for (int j = threadIdx.x; j < 512; j += 256) {
        float v = (j == 0) ? 1.0f : tab[(size_t)blk * IN_SZ + (j - 1)];
        tbt[(size_t)blk * 512 + j] = f2bf(v);
    }
    if (threadIdx.x == 0) tc[blk] = tab[(size_t)blk * IN_SZ + 511];
    if (blk < 513) {
        for (int b = threadIdx.x; b < B_SZ; b += 256)
            xhT[(size_t)blk * B_SZ + b] =
                (blk == 0) ? 1.0f : img[(size_t)b * IN_SZ + (blk - 1)];
    }
}

// -------- prep3: wrowT[j][h] = W1[(h*513+512)*513 + j]  (513 x 128 f32) ----
__global__ __launch_bounds__(256) void prep3_kernel(
    const float* __restrict__ w1, float* __restrict__ wrowT)
{
    const int idx = blockIdx.x * 256 + threadIdx.x;
    if (idx < 513 * 128) {
        const int j = idx >> 7, h = idx & 127;
        wrowT[idx] = w1[((size_t)h * 513 + 512) * 513 + j];
    }
}

// ---------------- main fused GEMM: B direct-to-register, A reg-staged ------
// BM=128, BN=256, BK=32. 8 waves (2M x 4N), wave-tile 64x64.
// A: fp32 vector load -> cvt -> swizzled ds_write (3-buf, 24 KB total).
// B: per-wave global->register fragments (t_hat is L2-resident), dbuf regs.
// No global_load_lds, no vmcnt asm; barrier = lgkmcnt(0) + s_barrier only.
__global__ __launch_bounds__(512, 3) void gemm_fused(
    const float* __restrict__ w1, const unsigned short* __restrict__ tbt,
    const float* __restrict__ xhT, const float* __restrict__ tc,
    float* __restrict__ y1acc)
{
    __shared__ unsigned short Als[3][128 * BK];   // 3 x 8 KB

    // T1: XCD swizzle, nwg=2048 (%8==0 -> simple bijective chunking)
    const int wgid = (blockIdx.x & 7) * 256 + (blockIdx.x >> 3);
    const int bm = wgid >> 2;             // 0..511
    const int bn = wgid & 3;              // 0..3
    const int n0 = bn * 256;
    const int h0    = bm >> 2;            // block fully inside one h
    const int ibase = (bm & 3) * 128;
    const int tid  = threadIdx.x;
    const int wv   = tid >> 6;
    const int wr   = wv >> 2;             // 0..1
    const int wc   = wv & 3;              // 0..3
    const int lane = tid & 63;
    const int l15  = lane & 15;
    const int kg   = lane >> 4;

    // A staging: thread owns phys chunk p = tid; logical chunk pre-swizzled.
    const int ar  = tid >> 2;
    const int acl = (tid & 3) ^ ((ar >> 1) & 3);
    const float* asrcF = w1 + ((size_t)h0 * 513 + ibase + ar) * 513 + acl * 8;

    // A fragment read offsets (u16 units); phys chunk = kg ^ ((r>>1)&3)
    int aoffs[4];
    #pragma unroll
    for (int ms = 0; ms < 4; ++ms) {
        const int r = wr * 64 + ms * 16 + l15;
        aoffs[ms] = (r * 4 + (kg ^ ((r >> 1) & 3))) * 8;
    }

    // B direct fragment pointers: col = n0 + wc*64 + ns*16 + l15, k-base kg*8
    const unsigned short* bptr[4];
    #pragma unroll
    for (int ns = 0; ns < 4; ++ns)
        bptr[ns] = tbt + (size_t)(n0 + wc * 64 + ns * 16 + l15) * 512 + kg * 8;

    f32x4 acc[4][4] = {};
    f32x4u rAlo, rAhi;   // in-flight A slot (tile kt+2 data)
    bf16x8 fB[2][4];     // register-double-buffered B fragments

#define CVW8(DST, LO, HI) do {                                               \
        u16x8 u_;                                                            \
        u_[0] = f2bf((LO)[0]); u_[1] = f2bf((LO)[1]);                        \
        u_[2] = f2bf((LO)[2]); u_[3] = f2bf((LO)[3]);                        \
        u_[4] = f2bf((HI)[0]); u_[5] = f2bf((HI)[1]);                        \
        u_[6] = f2bf((HI)[2]); u_[7] = f2bf((HI)[3]);                        \
        *reinterpret_cast<u16x8*>(DST) = u_;                                 \
    } while (0)

    // ---- prologue: A(0),A(1) into LDS; rA <- A(2); fB[0] <- B(0) ----
    {
        const f32x4u t0lo = *reinterpret_cast<const f32x4u*>(asrcF);
        const f32x4u t0hi = *reinterpret_cast<const f32x4u*>(asrcF + 4);
        const f32x4u t1lo = *reinterpret_cast<const f32x4u*>(asrcF + 32);
        const f32x4u t1hi = *reinterpret_cast<const f32x4u*>(asrcF + 36);
        CVW8(&Als[0][tid * 8], t0lo, t0hi);
        CVW8(&Als[1][tid * 8], t1lo, t1hi);
        rAlo = *reinterpret_cast<const f32x4u*>(asrcF + 64);
        rAhi = *reinterpret_cast<const f32x4u*>(asrcF + 68);
        #pragma unroll
        for (int ns = 0; ns < 4; ++ns)
            fB[0][ns] = *reinterpret_cast<const bf16x8*>(bptr[ns]);
    }
    asm volatile("s_waitcnt lgkmcnt(0)" ::: "memory");
    __builtin_amdgcn_s_barrier();
    __builtin_amdgcn_sched_barrier(0);

    #pragma unroll
    for (int kt = 0; kt < NKT; ++kt) {
        const int cur = kt % 3;
        const unsigned short* ab = &Als[cur][0];

        // write A(kt+1) from rA (loaded one iteration ago), then reload rA.
        // buf (kt+1)%3 was last read at iter kt-2, certified 3 barriers ago.
        if (kt >= 1 && kt + 1 < NKT)
            CVW8(&Als[(kt + 1) % 3][tid * 8], rAlo, rAhi);
        if (kt + 2 < NKT) {
            const float* s_ = asrcF + (kt + 2) * 32;
            rAlo = *reinterpret_cast<const f32x4u*>(s_);
            rAhi = *reinterpret_cast<const f32x4u*>(s_ + 4);
        }

        // prefetch B(kt+1) fragments (consumed next iteration)
        if (kt + 1 < NKT) {
            #pragma unroll
            for (int ns = 0; ns < 4; ++ns)
                fB[(kt + 1) & 1][ns] =
                    *reinterpret_cast<const bf16x8*>(bptr[ns] + (kt + 1) * 32);
        }

        bf16x8 af[4];
        #pragma unroll
        for (int ms = 0; ms < 4; ++ms)
            af[ms] = *reinterpret_cast<const bf16x8*>(&ab[aoffs[ms]]);

        __builtin_amdgcn_s_setprio(1);
        #pragma unroll
        for (int ns = 0; ns < 4; ++ns)
            #pragma unroll
            for (int ms = 0; ms < 4; ++ms)
                acc[ms][ns] = __builtin_amdgcn_mfma_f32_16x16x32_bf16(
                    af[ms], fB[kt & 1][ns], acc[ms][ns], 0, 0, 0);
        __builtin_amdgcn_s_setprio(0);

        if (kt < NKT - 1) {
            // only LDS handoff needs the barrier; B prefetch + rA stay in
            // flight across it (no vmcnt drain).
            asm volatile("s_waitcnt lgkmcnt(0)" ::: "memory");
            __builtin_amdgcn_s_barrier();
            __builtin_amdgcn_sched_barrier(0);
        }
    }
#undef CVW8

    // ---- epilogue: + j=512 rank-1 term (fp32), reduce over i, one atomic --
    const size_t orow = (size_t)h0 * 513;
    float wcv[4][4];
    #pragma unroll
    for (int ms = 0; ms < 4; ++ms)
        #pragma unroll
        for (int v = 0; v < 4; ++v) {
            const int i_ = ibase + wr * 64 + ms * 16 + kg * 4 + v;
            wcv[ms][v] = w1[(orow + i_) * 513 + 512];
        }

    #pragma unroll
    for (int ns = 0; ns < 4; ++ns) {
        const int ncol = n0 + wc * 64 + ns * 16 + l15;
        const float tv = tc[ncol];
        float s0 = 0.f;
        #pragma unroll
        for (int ms = 0; ms < 4; ++ms) {
            const int i_ = ibase + wr * 64 + ms * 16 + kg * 4;
            #pragma unroll
            for (int v = 0; v < 4; ++v)
                s0 += (acc[ms][ns][v] + wcv[ms][v] * tv)
                      * xhT[(size_t)(i_ + v) * B_SZ + ncol];
        }
        s0 += __shfl_xor(s0, 16); s0 += __shfl_xor(s0, 32);
        if (lane < 16) atomicAdd(&y1acc[(size_t)ncol * HID + h0], s0);
    }
}

// -------- tail: y1acc[n,h] += x_hat[n,512] * sum_{j<=512} wrowT[j][h]*t_hat --
__global__ __launch_bounds__(128) void tail_kernel(
    const float* __restrict__ img, const float* __restrict__ tab,
    const float* __restrict__ wrowT, float* __restrict__ y1acc)
{
    __shared__ float tls[4][513];
    const int b0 = blockIdx.x * 4;
    const int h  = threadIdx.x;
    #pragma unroll
    for (int q = 0; q < 4; ++q)
        for (int j = h; j < 513; j += 128)
            tls[q][j] = (j == 0) ? 1.0f : tab[(size_t)(b0 + q) * IN_SZ + (j - 1)];
    __syncthreads();
    float a0 = 0.f, a1 = 0.f, a2 = 0.f, a3 = 0.f;
    #pragma unroll 8
    for (int j = 0; j < 513; ++j) {
        const float w = wrowT[j * 128 + h];
        a0 += w * tls[0][j]; a1 += w * tls[1][j];
        a2 += w * tls[2][j]; a3 += w * tls[3][j];
    }
    atomicAdd(&y1acc[(size_t)(b0 + 0) * HID + h], a0 * img[(size_t)(b0 + 0) * IN_SZ + 511]);
    atomicAdd(&y1acc[(size_t)(b0 + 1) * HID + h], a1 * img[(size_t)(b0 + 1) * IN_SZ + 511]);
    atomicAdd(&y1acc[(size_t)(b0 + 2) * HID + h], a2 * img[(size_t)(b0 + 2) * IN_SZ + 511]);
    atomicAdd(&y1acc[(size_t)(b0 + 3) * HID + h], a3 * img[(size_t)(b0 + 3) * IN_SZ + 511]);
}

// ---------------- fallback GEMM (fp32-A path, 513-K, needs only small ws) ---
__global__ __launch_bounds__(512, 4) void gemm_fused_fb(
    const float* __restrict__ w1, const unsigned short* __restrict__ tbt,
    const float* __restrict__ xhT, const float* __restrict__ tc,
    float* __restrict__ y1acc)
{
    __shared__ float          Afs[2][64 * BK];
    __shared__ unsigned short Bls[2][512 * BK];

    const int bm = blockIdx.x >> 1;
    const int bn = blockIdx.x & 1;
    const int m0 = bm * 64;
    const int n0 = bn * 512;
    const int tid  = threadIdx.x;
    const int wv   = tid >> 6;
    const int lane = tid & 63;
    const int l15  = lane & 15;
    const int kg   = lane >> 4;

    const int ar  = tid >> 3;
    const int acl = (tid & 7) ^ (ar & 7);
    const float* asrc = w1 + (size_t)(m0 + ar) * 513 + acl * 4;
    const int aBase = (wv * 64) * 4;

    const unsigned short* bsrc[4];
    int bBase[4];
    #pragma unroll
    for (int q = 0; q < 4; ++q) {
        const int p  = q * 512 + tid;
        const int r  = p >> 2;
        const int cl = (p & 3) ^ ((r >> 1) & 3);
        bsrc[q] = tbt + (size_t)(n0 + r) * 512 + cl * 8;
        bBase[q] = (q * 512 + wv * 64) * 8;
    }

    int aoff0[4], aoff1[4], boffs[4];
    #pragma unroll
    for (int ms = 0; ms < 4; ++ms) {
        const int r = ms * 16 + l15;
        aoff0[ms] = r * 32 + (((kg * 2) + 0) ^ (r & 7)) * 4;
        aoff1[ms] = r * 32 + (((kg * 2) + 1) ^ (r & 7)) * 4;
    }
    #pragma unroll
    for (int ns = 0; ns < 4; ++ns) {
        const int r = wv * 64 + ns * 16 + l15;
        boffs[ns] = ((r << 2) | (kg ^ ((r >> 1) & 3))) * 8;
    }

    f32x4 acc[4][4] = {};

#define STAGE_FB(BUF, KT) do {                                               \
        const int k32_ = (KT) * BK;                                          \
        _Pragma("unroll")                                                    \
        for (int q_ = 0; q_ < 4; ++q_)                                       \
            __builtin_amdgcn_global_load_lds(                                \
                (gu32*)(const void*)(bsrc[q_] + k32_),                       \
                (lu32*)(void*)&Bls[BUF][bBase[q_]], 16, 0, 0);               \
        __builtin_amdgcn_global_load_lds(                                    \
            (gu32*)(const void*)(asrc + k32_),                               \
            (lu32*)(void*)&Afs[BUF][aBase], 16, 0, 0);                       \
    } while (0)

    STAGE_FB(0, 0);
    __syncthreads();

    for (int kt = 0; kt < NKT; ++kt) {
        const int cur = kt & 1;
        if (kt + 1 < NKT) STAGE_FB(cur ^ 1, kt + 1);

        const float*          ab = &Afs[cur][0];
        const unsigned short* bb = &Bls[cur][0];
        bf16x8 bfr[4];
        #pragma unroll
        for (int ns = 0; ns < 4; ++ns)
            bfr[ns] = *reinterpret_cast<const bf16x8*>(&bb[boffs[ns]]);
        #pragma unroll
        for (int ms = 0; ms < 4; ++ms) {
            const f32x4 lo = *reinterpret_cast<const f32x4*>(&ab[aoff0[ms]]);
            const f32x4 hi = *reinterpret_cast<const f32x4*>(&ab[aoff1[ms]]);
            u16x8 u;
            u[0] = f2bf(lo[0]); u[1] = f2bf(lo[1]);
            u[2] = f2bf(lo[2]); u[3] = f2bf(lo[3]);
            u[4] = f2bf(hi[0]); u[5] = f2bf(hi[1]);
            u[6] = f2bf(hi[2]); u[7] = f2bf(hi[3]);
            const bf16x8 af = __builtin_bit_cast(bf16x8, u);
            #pragma unroll
            for (int ns = 0; ns < 4; ++ns)
                acc[ms][ns] = __builtin_amdgcn_mfma_f32_16x16x32_bf16(
                    af, bfr[ns], acc[ms][ns], 0, 0, 0);
        }
        __syncthreads();
    }
#undef STAGE_FB

    const int h0 = m0 / 513;
    const int mb = (h0 + 1) * 513;
    const bool cross = (mb < m0 + 64);

    float wcv[4][4];
    #pragma unroll
    for (int ms = 0; ms < 4; ++ms)
        #pragma unroll
        for (int v = 0; v < 4; ++v)
            wcv[ms][v] = w1[(size_t)(m0 + ms * 16 + kg * 4 + v) * 513 + 512];

    #pragma unroll
    for (int ns = 0; ns < 4; ++ns) {
        const int ncol = n0 + wv * 64 + ns * 16 + l15;
        const float tv = tc[ncol];
        float s0 = 0.f, s1 = 0.f;
        #pragma unroll
        for (int ms = 0; ms < 4; ++ms) {
            #pragma unroll
            for (int v = 0; v < 4; ++v) {
                const int m = m0 + ms * 16 + kg * 4 + v;
                const bool lo = (m < mb);
                const int i = lo ? (m - h0 * 513) : (m - mb);
                const float val = (acc[ms][ns][v] + wcv[ms][v] * tv)
                                  * xhT[(size_t)i * B_SZ + ncol];
                if (lo) s0 += val; else s1 += val;
            }
        }
        s0 += __shfl_xor(s0, 16); s0 += __shfl_xor(s0, 32);
        if (lane < 16) atomicAdd(&y1acc[(size_t)ncol * HID + h0], s0);
        if (cross) {
            s1 += __shfl_xor(s1, 16); s1 += __shfl_xor(s1, 32);
            if (lane < 16 && (h0 + 1) < HID)
                atomicAdd(&y1acc[(size_t)ncol * HID + h0 + 1], s1);
        }
    }
}

// ---------------- MLP tail ----------------
__global__ __launch_bounds__(128) void mlp_kernel(
    const float* __restrict__ y1acc, const float* __restrict__ b1,
    const float* __restrict__ W2, const float* __restrict__ b2,
    const float* __restrict__ W3, const float* __restrict__ b3,
    float* __restrict__ out)
{
    __shared__ float y1r[HID];
    __shared__ float y2r[HID];
    const int b = blockIdx.x;
    const int h = threadIdx.x;
    y1r[h] = y1acc[(size_t)b * HID + h] + b1[h];
    __syncthreads();
    float a = b2[h];
    const float* w2r = W2 + (size_t)h * HID;
    #pragma unroll 8
    for (int k = 0; k < HID; ++k) a += w2r[k] * y1r[k];
    y2r[h] = tanhf(a);
    __syncthreads();
    if (h < OUT_SZ) {
        float a3 = b3[h];
        const float* w3r = W3 + (size_t)h * HID;
        #pragma unroll 8
        for (int k = 0; k < HID; ++k) a3 += w3r[k] * y2r[k];
        out[(size_t)b * OUT_SZ + h] = fmaxf(a3, 0.f);
    }
}

extern "C" void kernel_launch(void* const* d_in, const int* in_sizes, int n_in,
                              void* d_out, int out_size, void* d_ws, size_t ws_size,
                              hipStream_t stream) {
    const float* img = (const float*)d_in[0];
    const float* tab = (const float*)d_in[1];
    const float* W1  = (const float*)d_in[2];
    const float* b1  = (const float*)d_in[3];
    const float* W2  = (const float*)d_in[4];
    const float* b2  = (const float*)d_in[5];
    const float* W3  = (const float*)d_in[6];
    const float* b3  = (const float*)d_in[7];
    float* out = (float*)d_out;

    char* ws = (char*)d_ws;
    float*          y1acc = (float*)ws;                        // 524288 B
    unsigned short* tbt   = (unsigned short*)(ws + 524288);    // 1048576 B
    float*          xhT   = (float*)(ws + 1572864);            // 2101248 B (513x1024)
    float*          tc    = (float*)(ws + 3674112);            // 4096 B
    float*          wrowT = (float*)(ws + 3678208);            // 262656 B (513x128)
    const size_t need = 3678208ULL + 262656ULL;

    hipMemsetAsync(y1acc, 0, (size_t)B_SZ * HID * sizeof(float), stream);
    prep_kernel<<<dim3(1024), dim3(256), 0, stream>>>(img, tab, tbt, xhT, tc);
    if (ws_size >= need) {
        prep3_kernel<<<dim3(257), dim3(256), 0, stream>>>(W1, wrowT);
        gemm_fused<<<dim3(2048), dim3(512), 0, stream>>>(W1, tbt, xhT, tc, y1acc);
        tail_kernel<<<dim3(256), dim3(128), 0, stream>>>(img, tab, wrowT, y1acc);
    } else {
        gemm_fused_fb<<<dim3(2052), dim3(512), 0, stream>>>(W1, tbt, xhT, tc, y1acc);
    }
    mlp_kernel<<<dim3(1024), dim3(128), 0, stream>>>(y1acc, b1, W2, b2, W3, b3, out);
}

// Round 12
// 237.801 us; speedup vs baseline: 1.0679x; 1.0679x over previous
//
#include <hip/hip_runtime.h>
#include <hip/hip_bf16.h>

typedef __bf16 bf16x8 __attribute__((ext_vector_type(8)));
typedef float f32x4 __attribute__((ext_vector_type(4)));
typedef float f32x4u __attribute__((ext_vector_type(4), aligned(4)));
typedef unsigned short u16x8 __attribute__((ext_vector_type(8)));

typedef __attribute__((address_space(1))) const unsigned int gu32;
typedef __attribute__((address_space(3))) unsigned int lu32;

#define B_SZ   1024
#define IN_SZ  512
#define HID    128
#define OUT_SZ 64
#define BK     32
#define NKT    16        // K main loop = 512
#define M2     65536     // 128 h x 512 i   (main GEMM M, power of 2)

static __device__ __forceinline__ unsigned short f2bf(float f) {
    __hip_bfloat16 h = __float2bfloat16(f);
    return *reinterpret_cast<unsigned short*>(&h);
}

// ---------------- prep: t_hat bf16 [1024][512], tc, xhT [513][1024] --------
__global__ __launch_bounds__(256) void prep_kernel(
    const float* __restrict__ img, const float* __restrict__ tab,
    unsigned short* __restrict__ tbt, float* __restrict__ xhT,
    float* __restrict__ tc)
{
    const int blk = blockIdx.x;   // 0..1023
    for (int j = threadIdx.x; j < 512; j += 256) {
        float v = (j == 0) ? 1.0f : tab[(size_t)blk * IN_SZ + (j - 1)];
        tbt[(size_t)blk * 512 + j] = f2bf(v);
    }
    if (threadIdx.x == 0) tc[blk] = tab[(size_t)blk * IN_SZ + 511];
    if (blk < 513) {
        for (int b = threadIdx.x; b < B_SZ; b += 256)
            xhT[(size_t)blk * B_SZ + b] =
                (blk == 0) ? 1.0f : img[(size_t)b * IN_SZ + (blk - 1)];
    }
}

// -------- prep2: W1 -> w1c bf16 [65536][512]; row r=(h<<9)+i <- W1[h*513+i] -
__global__ __launch_bounds__(256) void prep2_kernel(
    const float* __restrict__ w1, unsigned short* __restrict__ w1c)
{
    const long long gid = (long long)blockIdx.x * 256 + threadIdx.x;
    const int r  = (int)(gid >> 6);                 // 0..65535
    const int c8 = ((int)gid & 63) << 3;
    const size_t srow = (size_t)(r >> 9) * 513 + (r & 511);
    const float* src = w1 + srow * 513 + c8;
    const f32x4u lo = *reinterpret_cast<const f32x4u*>(src);
    const f32x4u hi = *reinterpret_cast<const f32x4u*>(src + 4);
    u16x8 u;
    u[0] = f2bf(lo[0]); u[1] = f2bf(lo[1]); u[2] = f2bf(lo[2]); u[3] = f2bf(lo[3]);
    u[4] = f2bf(hi[0]); u[5] = f2bf(hi[1]); u[6] = f2bf(hi[2]); u[7] = f2bf(hi[3]);
    *reinterpret_cast<u16x8*>(w1c + (size_t)r * 512 + c8) = u;
}

// -------- prep3: wrowT[j][h] = W1[(h*513+512)*513 + j]  (513 x 128 f32) ----
__global__ __launch_bounds__(256) void prep3_kernel(
    const float* __restrict__ w1, float* __restrict__ wrowT)
{
    const int idx = blockIdx.x * 256 + threadIdx.x;
    if (idx < 513 * 128) {
        const int j = idx >> 7, h = idx & 127;
        wrowT[idx] = w1[((size_t)h * 513 + 512) * 513 + j];
    }
}

// ---------------- main fused GEMM: BM=BN=256, 1024 threads, 16 waves -------
// Wave-tile 64x64 (acc 64 regs, R9's proven shape). Both operands staged via
// global_load_lds (1 chunk/thread/iter each), 3-buf, issued 2 iters ahead,
// uniform counted vmcnt(2). Staged bytes: 270 MB (A bf16 x4) + 256 MB (B).
__global__ __launch_bounds__(1024, 4) void gemm_fused(
    const float* __restrict__ w1, const unsigned short* __restrict__ w1c,
    const unsigned short* __restrict__ tbt,
    const float* __restrict__ xhT, const float* __restrict__ tc,
    float* __restrict__ y1acc)
{
    __shared__ unsigned short Als[3][256 * BK];   // 3 x 16 KB
    __shared__ unsigned short Bls[3][256 * BK];   // 3 x 16 KB

    // T1: XCD swizzle, nwg=1024 (%8==0), cpx=128
    const int wgid = (blockIdx.x & 7) * 128 + (blockIdx.x >> 3);
    const int bm = wgid >> 2;             // 0..255
    const int bn = wgid & 3;              // 0..3
    const int m0 = bm * 256;              // m2-space; block inside one h
    const int n0 = bn * 256;
    const int h0    = bm >> 1;
    const int ibase = (bm & 1) * 256;
    const int tid  = threadIdx.x;
    const int wv   = tid >> 6;            // 0..15
    const int wr   = wv >> 2;             // 0..3
    const int wc   = wv & 3;              // 0..3
    const int lane = tid & 63;
    const int l15  = lane & 15;
    const int kg   = lane >> 4;

    // staging: thread owns phys chunk p = tid (256 rows x 4 chunks each op);
    // source pre-swizzled (cl = (p&3) ^ ((r>>1)&3)), dest linear.
    const unsigned short* asrc;
    const unsigned short* bsrc;
    {
        const int r  = tid >> 2;
        const int cl = (tid & 3) ^ ((r >> 1) & 3);
        asrc = w1c + (size_t)(m0 + r) * 512 + cl * 8;
        bsrc = tbt + (size_t)(n0 + r) * 512 + cl * 8;
    }
    const int sBase = (wv * 64) * 8;      // wave-uniform dst (u16)

    // fragment read offsets (u16 units); phys chunk = kg ^ ((r>>1)&3)
    int aoffs[4], boffs[4];
    #pragma unroll
    for (int ms = 0; ms < 4; ++ms) {
        const int r = wr * 64 + ms * 16 + l15;
        aoffs[ms] = (r * 4 + (kg ^ ((r >> 1) & 3))) * 8;
    }
    #pragma unroll
    for (int ns = 0; ns < 4; ++ns) {
        const int r = wc * 64 + ns * 16 + l15;
        boffs[ns] = (r * 4 + (kg ^ ((r >> 1) & 3))) * 8;
    }

    f32x4 acc[4][4] = {};

#define STG(BUF, KT) do {                                                    \
        const int k32_ = (KT) * BK;                                          \
        __builtin_amdgcn_global_load_lds(                                    \
            (gu32*)(const void*)(asrc + k32_),                               \
            (lu32*)(void*)&Als[BUF][sBase], 16, 0, 0);                       \
        __builtin_amdgcn_global_load_lds(                                    \
            (gu32*)(const void*)(bsrc + k32_),                               \
            (lu32*)(void*)&Bls[BUF][sBase], 16, 0, 0);                       \
    } while (0)

    STG(0, 0);
    STG(1, 1);

    #pragma unroll
    for (int kt = 0; kt < NKT; ++kt) {
        // counted vmcnt: drains exactly the pair issued 2 iters ago (tile kt);
        // the newer <=4 loads stay in flight across the barrier.
        if (kt == NKT - 1) asm volatile("s_waitcnt vmcnt(0)" ::: "memory");
        else               asm volatile("s_waitcnt vmcnt(2)" ::: "memory");
        __builtin_amdgcn_s_barrier();
        __builtin_amdgcn_sched_barrier(0);

        if (kt + 2 < NKT) STG((kt + 2) % 3, kt + 2);   // overwrites buf[kt-1]

        const int cur = kt % 3;
        const unsigned short* ab = &Als[cur][0];
        const unsigned short* bb = &Bls[cur][0];
        bf16x8 af[4], bfr[4];
        #pragma unroll
        for (int ms = 0; ms < 4; ++ms)
            af[ms] = *reinterpret_cast<const bf16x8*>(&ab[aoffs[ms]]);
        #pragma unroll
        for (int ns = 0; ns < 4; ++ns)
            bfr[ns] = *reinterpret_cast<const bf16x8*>(&bb[boffs[ns]]);
        __builtin_amdgcn_s_setprio(1);
        #pragma unroll
        for (int ms = 0; ms < 4; ++ms)
            #pragma unroll
            for (int ns = 0; ns < 4; ++ns)
                acc[ms][ns] = __builtin_amdgcn_mfma_f32_16x16x32_bf16(
                    af[ms], bfr[ns], acc[ms][ns], 0, 0, 0);
        __builtin_amdgcn_s_setprio(0);
    }
#undef STG

    // ---- epilogue: + j=512 rank-1 term (fp32), reduce over i, one atomic --
    const size_t orow = (size_t)h0 * 513;
    float wcv[4][4];
    #pragma unroll
    for (int ms = 0; ms < 4; ++ms)
        #pragma unroll
        for (int v = 0; v < 4; ++v) {
            const int i_ = ibase + wr * 64 + ms * 16 + kg * 4 + v;
            wcv[ms][v] = w1[(orow + i_) * 513 + 512];
        }

    #pragma unroll
    for (int ns = 0; ns < 4; ++ns) {
        const int ncol = n0 + wc * 64 + ns * 16 + l15;
        const float tv = tc[ncol];
        float s0 = 0.f;
        #pragma unroll
        for (int ms = 0; ms < 4; ++ms) {
            const int i_ = ibase + wr * 64 + ms * 16 + kg * 4;
            #pragma unroll
            for (int v = 0; v < 4; ++v)
                s0 += (acc[ms][ns][v] + wcv[ms][v] * tv)
                      * xhT[(size_t)(i_ + v) * B_SZ + ncol];
        }
        s0 += __shfl_xor(s0, 16); s0 += __shfl_xor(s0, 32);
        if (lane < 16) atomicAdd(&y1acc[(size_t)ncol * HID + h0], s0);
    }
}

// -------- tail: y1acc[n,h] += x_hat[n,512] * sum_{j<=512} wrowT[j][h]*t_hat --
__global__ __launch_bounds__(128) void tail_kernel(
    const float* __restrict__ img, const float* __restrict__ tab,
    const float* __restrict__ wrowT, float* __restrict__ y1acc)
{
    __shared__ float tls[4][513];
    const int b0 = blockIdx.x * 4;
    const int h  = threadIdx.x;
    #pragma unroll
    for (int q = 0; q < 4; ++q)
        for (int j = h; j < 513; j += 128)
            tls[q][j] = (j == 0) ? 1.0f : tab[(size_t)(b0 + q) * IN_SZ + (j - 1)];
    __syncthreads();
    float a0 = 0.f, a1 = 0.f, a2 = 0.f, a3 = 0.f;
    #pragma unroll 8
    for (int j = 0; j < 513; ++j) {
        const float w = wrowT[j * 128 + h];
        a0 += w * tls[0][j]; a1 += w * tls[1][j];
        a2 += w * tls[2][j]; a3 += w * tls[3][j];
    }
    atomicAdd(&y1acc[(size_t)(b0 + 0) * HID + h], a0 * img[(size_t)(b0 + 0) * IN_SZ + 511]);
    atomicAdd(&y1acc[(size_t)(b0 + 1) * HID + h], a1 * img[(size_t)(b0 + 1) * IN_SZ + 511]);
    atomicAdd(&y1acc[(size_t)(b0 + 2) * HID + h], a2 * img[(size_t)(b0 + 2) * IN_SZ + 511]);
    atomicAdd(&y1acc[(size_t)(b0 + 3) * HID + h], a3 * img[(size_t)(b0 + 3) * IN_SZ + 511]);
}

// ---------------- fallback GEMM (fp32-A path, 513-K, needs only small ws) ---
__global__ __launch_bounds__(512, 4) void gemm_fused_fb(
    const float* __restrict__ w1, const unsigned short* __restrict__ tbt,
    const float* __restrict__ xhT, const float* __restrict__ tc,
    float* __restrict__ y1acc)
{
    __shared__ float          Afs[2][64 * BK];
    __shared__ unsigned short Bls[2][512 * BK];

    const int bm = blockIdx.x >> 1;
    const int bn = blockIdx.x & 1;
    const int m0 = bm * 64;
    const int n0 = bn * 512;
    const int tid  = threadIdx.x;
    const int wv   = tid >> 6;
    const int lane = tid & 63;
    const int l15  = lane & 15;
    const int kg   = lane >> 4;

    const int ar  = tid >> 3;
    const int acl = (tid & 7) ^ (ar & 7);
    const float* asrc = w1 + (size_t)(m0 + ar) * 513 + acl * 4;
    const int aBase = (wv * 64) * 4;

    const unsigned short* bsrc[4];
    int bBase[4];
    #pragma unroll
    for (int q = 0; q < 4; ++q) {
        const int p  = q * 512 + tid;
        const int r  = p >> 2;
        const int cl = (p & 3) ^ ((r >> 1) & 3);
        bsrc[q] = tbt + (size_t)(n0 + r) * 512 + cl * 8;
        bBase[q] = (q * 512 + wv * 64) * 8;
    }

    int aoff0[4], aoff1[4], boffs[4];
    #pragma unroll
    for (int ms = 0; ms < 4; ++ms) {
        const int r = ms * 16 + l15;
        aoff0[ms] = r * 32 + (((kg * 2) + 0) ^ (r & 7)) * 4;
        aoff1[ms] = r * 32 + (((kg * 2) + 1) ^ (r & 7)) * 4;
    }
    #pragma unroll
    for (int ns = 0; ns < 4; ++ns) {
        const int r = wv * 64 + ns * 16 + l15;
        boffs[ns] = ((r << 2) | (kg ^ ((r >> 1) & 3))) * 8;
    }

    f32x4 acc[4][4] = {};

#define STAGE_FB(BUF, KT) do {                                               \
        const int k32_ = (KT) * BK;                                          \
        _Pragma("unroll")                                                    \
        for (int q_ = 0; q_ < 4; ++q_)                                       \
            __builtin_amdgcn_global_load_lds(                                \
                (gu32*)(const void*)(bsrc[q_] + k32_),                       \
                (lu32*)(void*)&Bls[BUF][bBase[q_]], 16, 0, 0);               \
        __builtin_amdgcn_global_load_lds(                                    \
            (gu32*)(const void*)(asrc + k32_),                               \
            (lu32*)(void*)&Afs[BUF][aBase], 16, 0, 0);                       \
    } while (0)

    STAGE_FB(0, 0);
    __syncthreads();

    for (int kt = 0; kt < NKT; ++kt) {
        const int cur = kt & 1;
        if (kt + 1 < NKT) STAGE_FB(cur ^ 1, kt + 1);

        const float*          ab = &Afs[cur][0];
        const unsigned short* bb = &Bls[cur][0];
        bf16x8 bfr[4];
        #pragma unroll
        for (int ns = 0; ns < 4; ++ns)
            bfr[ns] = *reinterpret_cast<const bf16x8*>(&bb[boffs[ns]]);
        #pragma unroll
        for (int ms = 0; ms < 4; ++ms) {
            const f32x4 lo = *reinterpret_cast<const f32x4*>(&ab[aoff0[ms]]);
            const f32x4 hi = *reinterpret_cast<const f32x4*>(&ab[aoff1[ms]]);
            u16x8 u;
            u[0] = f2bf(lo[0]); u[1] = f2bf(lo[1]);
            u[2] = f2bf(lo[2]); u[3] = f2bf(lo[3]);
            u[4] = f2bf(hi[0]); u[5] = f2bf(hi[1]);
            u[6] = f2bf(hi[2]); u[7] = f2bf(hi[3]);
            const bf16x8 af = __builtin_bit_cast(bf16x8, u);
            #pragma unroll
            for (int ns = 0; ns < 4; ++ns)
                acc[ms][ns] = __builtin_amdgcn_mfma_f32_16x16x32_bf16(
                    af, bfr[ns], acc[ms][ns], 0, 0, 0);
        }
        __syncthreads();
    }
#undef STAGE_FB

    const int h0 = m0 / 513;
    const int mb = (h0 + 1) * 513;
    const bool cross = (mb < m0 + 64);

    float wcv[4][4];
    #pragma unroll
    for (int ms = 0; ms < 4; ++ms)
        #pragma unroll
        for (int v = 0; v < 4; ++v)
            wcv[ms][v] = w1[(size_t)(m0 + ms * 16 + kg * 4 + v) * 513 + 512];

    #pragma unroll
    for (int ns = 0; ns < 4; ++ns) {
        const int ncol = n0 + wv * 64 + ns * 16 + l15;
        const float tv = tc[ncol];
        float s0 = 0.f, s1 = 0.f;
        #pragma unroll
        for (int ms = 0; ms < 4; ++ms) {
            #pragma unroll
            for (int v = 0; v < 4; ++v) {
                const int m = m0 + ms * 16 + kg * 4 + v;
                const bool lo = (m < mb);
                const int i = lo ? (m - h0 * 513) : (m - mb);
                const float val = (acc[ms][ns][v] + wcv[ms][v] * tv)
                                  * xhT[(size_t)i * B_SZ + ncol];
                if (lo) s0 += val; else s1 += val;
            }
        }
        s0 += __shfl_xor(s0, 16); s0 += __shfl_xor(s0, 32);
        if (lane < 16) atomicAdd(&y1acc[(size_t)ncol * HID + h0], s0);
        if (cross) {
            s1 += __shfl_xor(s1, 16); s1 += __shfl_xor(s1, 32);
            if (lane < 16 && (h0 + 1) < HID)
                atomicAdd(&y1acc[(size_t)ncol * HID + h0 + 1], s1);
        }
    }
}

// ---------------- MLP tail ----------------
__global__ __launch_bounds__(128) void mlp_kernel(
    const float* __restrict__ y1acc, const float* __restrict__ b1,
    const float* __restrict__ W2, const float* __restrict__ b2,
    const float* __restrict__ W3, const float* __restrict__ b3,
    float* __restrict__ out)
{
    __shared__ float y1r[HID];
    __shared__ float y2r[HID];
    const int b = blockIdx.x;
    const int h = threadIdx.x;
    y1r[h] = y1acc[(size_t)b * HID + h] + b1[h];
    __syncthreads();
    float a = b2[h];
    const float* w2r = W2 + (size_t)h * HID;
    #pragma unroll 8
    for (int k = 0; k < HID; ++k) a += w2r[k] * y1r[k];
    y2r[h] = tanhf(a);
    __syncthreads();
    if (h < OUT_SZ) {
        float a3 = b3[h];
        const float* w3r = W3 + (size_t)h * HID;
        #pragma unroll 8
        for (int k = 0; k < HID; ++k) a3 += w3r[k] * y2r[k];
        out[(size_t)b * OUT_SZ + h] = fmaxf(a3, 0.f);
    }
}

extern "C" void kernel_launch(void* const* d_in, const int* in_sizes, int n_in,
                              void* d_out, int out_size, void* d_ws, size_t ws_size,
                              hipStream_t stream) {
    const float* img = (const float*)d_in[0];
    const float* tab = (const float*)d_in[1];
    const float* W1  = (const float*)d_in[2];
    const float* b1  = (const float*)d_in[3];
    const float* W2  = (const float*)d_in[4];
    const float* b2  = (const float*)d_in[5];
    const float* W3  = (const float*)d_in[6];
    const float* b3  = (const float*)d_in[7];
    float* out = (float*)d_out;

    char* ws = (char*)d_ws;
    float*          y1acc = (float*)ws;                        // 524288 B
    unsigned short* tbt   = (unsigned short*)(ws + 524288);    // 1048576 B
    float*          xhT   = (float*)(ws + 1572864);            // 2101248 B (513x1024)
    float*          tc    = (float*)(ws + 3674112);            // 4096 B
    float*          wrowT = (float*)(ws + 3678208);            // 262656 B (513x128)
    unsigned short* w1c   = (unsigned short*)(ws + 3940864);   // 67108864 B (65536x512)
    const size_t need = 3940864ULL + 67108864ULL;

    hipMemsetAsync(y1acc, 0, (size_t)B_SZ * HID * sizeof(float), stream);
    prep_kernel<<<dim3(1024), dim3(256), 0, stream>>>(img, tab, tbt, xhT, tc);
    if (ws_size >= need) {
        prep2_kernel<<<dim3(M2 * 64 / 256), dim3(256), 0, stream>>>(W1, w1c);
        prep3_kernel<<<dim3(257), dim3(256), 0, stream>>>(W1, wrowT);
        gemm_fused<<<dim3(1024), dim3(1024), 0, stream>>>(W1, w1c, tbt, xhT, tc, y1acc);
        tail_kernel<<<dim3(256), dim3(128), 0, stream>>>(img, tab, wrowT, y1acc);
    } else {
        gemm_fused_fb<<<dim3(2052), dim3(512), 0, stream>>>(W1, tbt, xhT, tc, y1acc);
    }
    mlp_kernel<<<dim3(1024), dim3(128), 0, stream>>>(y1acc, b1, W2, b2, W3, b3, out);
}

// Round 13
// 186.107 us; speedup vs baseline: 1.3646x; 1.2778x over previous
//
#include <hip/hip_runtime.h>
#include <hip/hip_bf16.h>

typedef __bf16 bf16x8 __attribute__((ext_vector_type(8)));
typedef float f32x4 __attribute__((ext_vector_type(4)));
typedef float f32x4u __attribute__((ext_vector_type(4), aligned(4)));
typedef unsigned short u16x8 __attribute__((ext_vector_type(8)));

typedef __attribute__((address_space(1))) const unsigned int gu32;
typedef __attribute__((address_space(3))) unsigned int lu32;

#define B_SZ   1024
#define IN_SZ  512
#define HID    128
#define OUT_SZ 64
#define BK     32
#define NKT    16        // K main loop = 512
#define M2     65536     // 128 h x 512 i

static __device__ __forceinline__ unsigned short f2bf(float f) {
    __hip_bfloat16 h = __float2bfloat16(f);
    return *reinterpret_cast<unsigned short*>(&h);
}

// ---- prep: t_hat bf16 [1024][512], tc, xhT [513][1024], wrowT [513][128] --
__global__ __launch_bounds__(256) void prep_kernel(
    const float* __restrict__ img, const float* __restrict__ tab,
    unsigned short* __restrict__ tbt, float* __restrict__ xhT,
    float* __restrict__ tc, const float* __restrict__ w1,
    float* __restrict__ wrowT)
{
    const int blk = blockIdx.x;   // 0..1023
    for (int j = threadIdx.x; j < 512; j += 256) {
        float v = (j == 0) ? 1.0f : tab[(size_t)blk * IN_SZ + (j - 1)];
        tbt[(size_t)blk * 512 + j] = f2bf(v);
    }
    if (threadIdx.x == 0) tc[blk] = tab[(size_t)blk * IN_SZ + 511];
    if (blk < 513) {
        for (int b = threadIdx.x; b < B_SZ; b += 256)
            xhT[(size_t)blk * B_SZ + b] =
                (blk == 0) ? 1.0f : img[(size_t)b * IN_SZ + (blk - 1)];
    }
    if (blk < 257) {   // merged prep3: wrowT[j][h] = W1[(h*513+512)*513 + j]
        const int idx = blk * 256 + threadIdx.x;
        if (idx < 513 * 128) {
            const int j = idx >> 7, h = idx & 127;
            wrowT[idx] = w1[((size_t)h * 513 + 512) * 513 + j];
        }
    }
}

// ---------------- main fused GEMM (R10 verbatim): fused fp32->bf16 A -------
__global__ __launch_bounds__(512, 4) void gemm_fused(
    const float* __restrict__ w1, const unsigned short* __restrict__ tbt,
    const float* __restrict__ xhT, const float* __restrict__ tc,
    float* __restrict__ y1acc)
{
    __shared__ unsigned short Als[3][128 * BK];   // 3 x 8 KB
    __shared__ unsigned short Bls[3][256 * BK];   // 3 x 16 KB

    const int wgid = (blockIdx.x & 7) * 256 + (blockIdx.x >> 3);
    const int bm = wgid >> 2;
    const int bn = wgid & 3;
    const int n0 = bn * 256;
    const int h0    = bm >> 2;
    const int ibase = (bm & 3) * 128;
    const int tid  = threadIdx.x;
    const int wv   = tid >> 6;
    const int wr   = wv >> 2;
    const int wc   = wv & 3;
    const int lane = tid & 63;
    const int l15  = lane & 15;
    const int kg   = lane >> 4;

    const int ar  = tid >> 2;
    const int acl = (tid & 3) ^ ((ar >> 1) & 3);
    const float* asrcF = w1 + ((size_t)h0 * 513 + ibase + ar) * 513 + acl * 8;

    const unsigned short* bsrc[2];
    int bBase[2];
    #pragma unroll
    for (int q = 0; q < 2; ++q) {
        const int p  = q * 512 + tid;
        const int r  = p >> 2;
        const int cl = (p & 3) ^ ((r >> 1) & 3);
        bsrc[q] = tbt + (size_t)(n0 + r) * 512 + cl * 8;
        bBase[q] = (q * 512 + wv * 64) * 8;
    }

    int aoffs[4], boffs[4];
    #pragma unroll
    for (int ms = 0; ms < 4; ++ms) {
        const int r = wr * 64 + ms * 16 + l15;
        aoffs[ms] = (r * 4 + (kg ^ ((r >> 1) & 3))) * 8;
    }
    #pragma unroll
    for (int ns = 0; ns < 4; ++ns) {
        const int r = wc * 64 + ns * 16 + l15;
        boffs[ns] = (r * 4 + (kg ^ ((r >> 1) & 3))) * 8;
    }

    f32x4 acc[4][4] = {};
    f32x4u rAlo, rAhi;

#define STB(BUF, KT) do {                                                    \
        const int k32_ = (KT) * BK;                                          \
        _Pragma("unroll")                                                    \
        for (int q_ = 0; q_ < 2; ++q_)                                       \
            __builtin_amdgcn_global_load_lds(                                \
                (gu32*)(const void*)(bsrc[q_] + k32_),                       \
                (lu32*)(void*)&Bls[BUF][bBase[q_]], 16, 0, 0);               \
    } while (0)
#define CVW8(DST, LO, HI) do {                                               \
        u16x8 u_;                                                            \
        u_[0] = f2bf((LO)[0]); u_[1] = f2bf((LO)[1]);                        \
        u_[2] = f2bf((LO)[2]); u_[3] = f2bf((LO)[3]);                        \
        u_[4] = f2bf((HI)[0]); u_[5] = f2bf((HI)[1]);                        \
        u_[6] = f2bf((HI)[2]); u_[7] = f2bf((HI)[3]);                        \
        *reinterpret_cast<u16x8*>(DST) = u_;                                 \
    } while (0)

    {
        const f32x4u t0lo = *reinterpret_cast<const f32x4u*>(asrcF);
        const f32x4u t0hi = *reinterpret_cast<const f32x4u*>(asrcF + 4);
        const f32x4u t1lo = *reinterpret_cast<const f32x4u*>(asrcF + 32);
        const f32x4u t1hi = *reinterpret_cast<const f32x4u*>(asrcF + 36);
        CVW8(&Als[0][tid * 8], t0lo, t0hi);
        CVW8(&Als[1][tid * 8], t1lo, t1hi);
        STB(0, 0);
        STB(1, 1);
    }
    __syncthreads();

    #pragma unroll
    for (int kt = 0; kt < NKT; ++kt) {
        const int cur = kt % 3;
        const unsigned short* ab = &Als[cur][0];
        const unsigned short* bb = &Bls[cur][0];

        if (kt >= 1 && kt + 1 < NKT)
            CVW8(&Als[(kt + 1) % 3][tid * 8], rAlo, rAhi);
        if (kt + 2 < NKT) {
            const float* s_ = asrcF + (kt + 2) * 32;
            rAlo = *reinterpret_cast<const f32x4u*>(s_);
            rAhi = *reinterpret_cast<const f32x4u*>(s_ + 4);
        }

        bf16x8 af[4];
        #pragma unroll
        for (int ms = 0; ms < 4; ++ms)
            af[ms] = *reinterpret_cast<const bf16x8*>(&ab[aoffs[ms]]);
        __builtin_amdgcn_s_setprio(1);
        #pragma unroll
        for (int ns = 0; ns < 4; ++ns) {
            const bf16x8 bf = *reinterpret_cast<const bf16x8*>(&bb[boffs[ns]]);
            #pragma unroll
            for (int ms = 0; ms < 4; ++ms)
                acc[ms][ns] = __builtin_amdgcn_mfma_f32_16x16x32_bf16(
                    af[ms], bf, acc[ms][ns], 0, 0, 0);
        }
        __builtin_amdgcn_s_setprio(0);

        if (kt == NKT - 1) break;

        if (kt + 2 >= NKT) asm volatile("s_waitcnt vmcnt(0)" ::: "memory");
        else               asm volatile("s_waitcnt vmcnt(2)" ::: "memory");
        if (kt + 2 < NKT) STB((kt + 2) % 3, kt + 2);
        asm volatile("s_waitcnt lgkmcnt(0)" ::: "memory");
        __builtin_amdgcn_s_barrier();
        __builtin_amdgcn_sched_barrier(0);
    }
#undef STB
#undef CVW8

    const size_t orow = (size_t)h0 * 513;
    float wcv[4][4];
    #pragma unroll
    for (int ms = 0; ms < 4; ++ms)
        #pragma unroll
        for (int v = 0; v < 4; ++v) {
            const int i_ = ibase + wr * 64 + ms * 16 + kg * 4 + v;
            wcv[ms][v] = w1[(orow + i_) * 513 + 512];
        }

    #pragma unroll
    for (int ns = 0; ns < 4; ++ns) {
        const int ncol = n0 + wc * 64 + ns * 16 + l15;
        const float tv = tc[ncol];
        float s0 = 0.f;
        #pragma unroll
        for (int ms = 0; ms < 4; ++ms) {
            const int i_ = ibase + wr * 64 + ms * 16 + kg * 4;
            #pragma unroll
            for (int v = 0; v < 4; ++v)
                s0 += (acc[ms][ns][v] + wcv[ms][v] * tv)
                      * xhT[(size_t)(i_ + v) * B_SZ + ncol];
        }
        s0 += __shfl_xor(s0, 16); s0 += __shfl_xor(s0, 32);
        if (lane < 16) atomicAdd(&y1acc[(size_t)ncol * HID + h0], s0);
    }
}

// ---- merged tail + MLP: 4 batches/block, W2/W3 LDS-staged (padded) --------
// y1 = y1acc + b1 + x_hat[b,512]*(wrowT . t_hat_row)   [tail term]
// y2 = tanh(y1 @ W2^T + b2); out = relu(y2 @ W3^T + b3)
__global__ __launch_bounds__(128) void tailmlp_kernel(
    const float* __restrict__ img, const float* __restrict__ tab,
    const float* __restrict__ wrowT, const float* __restrict__ y1acc,
    const float* __restrict__ b1,
    const float* __restrict__ W2, const float* __restrict__ b2,
    const float* __restrict__ W3, const float* __restrict__ b3,
    float* __restrict__ out)
{
    __shared__ float tls[4][513];        //  8208 B
    __shared__ float W2p[128][129];      // 66048 B (pad kills bank conflicts)
    __shared__ float W3p[64][129];       // 33024 B
    __shared__ float y1ls[4][128];
    __shared__ float y2ls[4][128];

    const int b0 = blockIdx.x * 4;
    const int h  = threadIdx.x;          // 0..127

    // cooperative loads (coalesced)
    #pragma unroll
    for (int g = 0; g < 128; ++g) {      // W2: 16384 elems, 128 per thread
        const int idx = g * 128 + h;
        W2p[idx >> 7][idx & 127] = W2[idx];
    }
    #pragma unroll
    for (int g = 0; g < 64; ++g) {       // W3: 8192 elems
        const int idx = g * 128 + h;
        W3p[idx >> 7][idx & 127] = W3[idx];
    }
    #pragma unroll
    for (int q = 0; q < 4; ++q)
        for (int j = h; j < 513; j += 128)
            tls[q][j] = (j == 0) ? 1.0f : tab[(size_t)(b0 + q) * IN_SZ + (j - 1)];
    __syncthreads();

    // tail term + y1 assembly
    {
        float a0 = 0.f, a1 = 0.f, a2 = 0.f, a3 = 0.f;
        #pragma unroll 8
        for (int j = 0; j < 513; ++j) {
            const float w = wrowT[j * 128 + h];
            a0 += w * tls[0][j]; a1 += w * tls[1][j];
            a2 += w * tls[2][j]; a3 += w * tls[3][j];
        }
        const float bb = b1[h];
        y1ls[0][h] = y1acc[(size_t)(b0 + 0) * HID + h] + bb
                     + a0 * img[(size_t)(b0 + 0) * IN_SZ + 511];
        y1ls[1][h] = y1acc[(size_t)(b0 + 1) * HID + h] + bb
                     + a1 * img[(size_t)(b0 + 1) * IN_SZ + 511];
        y1ls[2][h] = y1acc[(size_t)(b0 + 2) * HID + h] + bb
                     + a2 * img[(size_t)(b0 + 2) * IN_SZ + 511];
        y1ls[3][h] = y1acc[(size_t)(b0 + 3) * HID + h] + bb
                     + a3 * img[(size_t)(b0 + 3) * IN_SZ + 511];
    }
    __syncthreads();

    // y2 = tanh(y1 @ W2^T + b2)
    {
        const float bb = b2[h];
        float s[4] = {bb, bb, bb, bb};
        #pragma unroll 16
        for (int k = 0; k < HID; ++k) {
            const float w = W2p[h][k];
            s[0] += w * y1ls[0][k]; s[1] += w * y1ls[1][k];
            s[2] += w * y1ls[2][k]; s[3] += w * y1ls[3][k];
        }
        #pragma unroll
        for (int q = 0; q < 4; ++q) y2ls[q][h] = tanhf(s[q]);
    }
    __syncthreads();

    // y3 = relu(y2 @ W3^T + b3)
    if (h < OUT_SZ) {
        const float bb = b3[h];
        float s[4] = {bb, bb, bb, bb};
        #pragma unroll 16
        for (int k = 0; k < HID; ++k) {
            const float w = W3p[h][k];
            s[0] += w * y2ls[0][k]; s[1] += w * y2ls[1][k];
            s[2] += w * y2ls[2][k]; s[3] += w * y2ls[3][k];
        }
        #pragma unroll
        for (int q = 0; q < 4; ++q)
            out[(size_t)(b0 + q) * OUT_SZ + h] = fmaxf(s[q], 0.f);
    }
}

// ---------------- fallback GEMM (fp32-A path, full 513-K) -------------------
__global__ __launch_bounds__(512, 4) void gemm_fused_fb(
    const float* __restrict__ w1, const unsigned short* __restrict__ tbt,
    const float* __restrict__ xhT, const float* __restrict__ tc,
    float* __restrict__ y1acc)
{
    __shared__ float          Afs[2][64 * BK];
    __shared__ unsigned short Bls[2][512 * BK];

    const int bm = blockIdx.x >> 1;
    const int bn = blockIdx.x & 1;
    const int m0 = bm * 64;
    const int n0 = bn * 512;
    const int tid  = threadIdx.x;
    const int wv   = tid >> 6;
    const int lane = tid & 63;
    const int l15  = lane & 15;
    const int kg   = lane >> 4;

    const int ar  = tid >> 3;
    const int acl = (tid & 7) ^ (ar & 7);
    const float* asrc = w1 + (size_t)(m0 + ar) * 513 + acl * 4;
    const int aBase = (wv * 64) * 4;

    const unsigned short* bsrc[4];
    int bBase[4];
    #pragma unroll
    for (int q = 0; q < 4; ++q) {
        const int p  = q * 512 + tid;
        const int r  = p >> 2;
        const int cl = (p & 3) ^ ((r >> 1) & 3);
        bsrc[q] = tbt + (size_t)(n0 + r) * 512 + cl * 8;
        bBase[q] = (q * 512 + wv * 64) * 8;
    }

    int aoff0[4], aoff1[4], boffs[4];
    #pragma unroll
    for (int ms = 0; ms < 4; ++ms) {
        const int r = ms * 16 + l15;
        aoff0[ms] = r * 32 + (((kg * 2) + 0) ^ (r & 7)) * 4;
        aoff1[ms] = r * 32 + (((kg * 2) + 1) ^ (r & 7)) * 4;
    }
    #pragma unroll
    for (int ns = 0; ns < 4; ++ns) {
        const int r = wv * 64 + ns * 16 + l15;
        boffs[ns] = ((r << 2) | (kg ^ ((r >> 1) & 3))) * 8;
    }

    f32x4 acc[4][4] = {};

#define STAGE_FB(BUF, KT) do {                                               \
        const int k32_ = (KT) * BK;                                          \
        _Pragma("unroll")                                                    \
        for (int q_ = 0; q_ < 4; ++q_)                                       \
            __builtin_amdgcn_global_load_lds(                                \
                (gu32*)(const void*)(bsrc[q_] + k32_),                       \
                (lu32*)(void*)&Bls[BUF][bBase[q_]], 16, 0, 0);               \
        __builtin_amdgcn_global_load_lds(                                    \
            (gu32*)(const void*)(asrc + k32_),                               \
            (lu32*)(void*)&Afs[BUF][aBase], 16, 0, 0);                       \
    } while (0)

    STAGE_FB(0, 0);
    __syncthreads();

    for (int kt = 0; kt < NKT; ++kt) {
        const int cur = kt & 1;
        if (kt + 1 < NKT) STAGE_FB(cur ^ 1, kt + 1);

        const float*          ab = &Afs[cur][0];
        const unsigned short* bb = &Bls[cur][0];
        bf16x8 bfr[4];
        #pragma unroll
        for (int ns = 0; ns < 4; ++ns)
            bfr[ns] = *reinterpret_cast<const bf16x8*>(&bb[boffs[ns]]);
        #pragma unroll
        for (int ms = 0; ms < 4; ++ms) {
            const f32x4 lo = *reinterpret_cast<const f32x4*>(&ab[aoff0[ms]]);
            const f32x4 hi = *reinterpret_cast<const f32x4*>(&ab[aoff1[ms]]);
            u16x8 u;
            u[0] = f2bf(lo[0]); u[1] = f2bf(lo[1]);
            u[2] = f2bf(lo[2]); u[3] = f2bf(lo[3]);
            u[4] = f2bf(hi[0]); u[5] = f2bf(hi[1]);
            u[6] = f2bf(hi[2]); u[7] = f2bf(hi[3]);
            const bf16x8 af = __builtin_bit_cast(bf16x8, u);
            #pragma unroll
            for (int ns = 0; ns < 4; ++ns)
                acc[ms][ns] = __builtin_amdgcn_mfma_f32_16x16x32_bf16(
                    af, bfr[ns], acc[ms][ns], 0, 0, 0);
        }
        __syncthreads();
    }
#undef STAGE_FB

    const int h0 = m0 / 513;
    const int mb = (h0 + 1) * 513;
    const bool cross = (mb < m0 + 64);

    float wcv[4][4];
    #pragma unroll
    for (int ms = 0; ms < 4; ++ms)
        #pragma unroll
        for (int v = 0; v < 4; ++v)
            wcv[ms][v] = w1[(size_t)(m0 + ms * 16 + kg * 4 + v) * 513 + 512];

    #pragma unroll
    for (int ns = 0; ns < 4; ++ns) {
        const int ncol = n0 + wv * 64 + ns * 16 + l15;
        const float tv = tc[ncol];
        float s0 = 0.f, s1 = 0.f;
        #pragma unroll
        for (int ms = 0; ms < 4; ++ms) {
            #pragma unroll
            for (int v = 0; v < 4; ++v) {
                const int m = m0 + ms * 16 + kg * 4 + v;
                const bool lo = (m < mb);
                const int i = lo ? (m - h0 * 513) : (m - mb);
                const float val = (acc[ms][ns][v] + wcv[ms][v] * tv)
                                  * xhT[(size_t)i * B_SZ + ncol];
                if (lo) s0 += val; else s1 += val;
            }
        }
        s0 += __shfl_xor(s0, 16); s0 += __shfl_xor(s0, 32);
        if (lane < 16) atomicAdd(&y1acc[(size_t)ncol * HID + h0], s0);
        if (cross) {
            s1 += __shfl_xor(s1, 16); s1 += __shfl_xor(s1, 32);
            if (lane < 16 && (h0 + 1) < HID)
                atomicAdd(&y1acc[(size_t)ncol * HID + h0 + 1], s1);
        }
    }
}

// ---------------- plain MLP (fallback path: no tail term) -------------------
__global__ __launch_bounds__(128) void mlp_kernel(
    const float* __restrict__ y1acc, const float* __restrict__ b1,
    const float* __restrict__ W2, const float* __restrict__ b2,
    const float* __restrict__ W3, const float* __restrict__ b3,
    float* __restrict__ out)
{
    __shared__ float y1r[HID];
    __shared__ float y2r[HID];
    const int b = blockIdx.x;
    const int h = threadIdx.x;
    y1r[h] = y1acc[(size_t)b * HID + h] + b1[h];
    __syncthreads();
    float a = b2[h];
    const float* w2r = W2 + (size_t)h * HID;
    #pragma unroll 8
    for (int k = 0; k < HID; ++k) a += w2r[k] * y1r[k];
    y2r[h] = tanhf(a);
    __syncthreads();
    if (h < OUT_SZ) {
        float a3 = b3[h];
        const float* w3r = W3 + (size_t)h * HID;
        #pragma unroll 8
        for (int k = 0; k < HID; ++k) a3 += w3r[k] * y2r[k];
        out[(size_t)b * OUT_SZ + h] = fmaxf(a3, 0.f);
    }
}

extern "C" void kernel_launch(void* const* d_in, const int* in_sizes, int n_in,
                              void* d_out, int out_size, void* d_ws, size_t ws_size,
                              hipStream_t stream) {
    const float* img = (const float*)d_in[0];
    const float* tab = (const float*)d_in[1];
    const float* W1  = (const float*)d_in[2];
    const float* b1  = (const float*)d_in[3];
    const float* W2  = (const float*)d_in[4];
    const float* b2  = (const float*)d_in[5];
    const float* W3  = (const float*)d_in[6];
    const float* b3  = (const float*)d_in[7];
    float* out = (float*)d_out;

    char* ws = (char*)d_ws;
    float*          y1acc = (float*)ws;                        // 524288 B
    unsigned short* tbt   = (unsigned short*)(ws + 524288);    // 1048576 B
    float*          xhT   = (float*)(ws + 1572864);            // 2101248 B (513x1024)
    float*          tc    = (float*)(ws + 3674112);            // 4096 B
    float*          wrowT = (float*)(ws + 3678208);            // 262656 B (513x128)
    const size_t need = 3678208ULL + 262656ULL;

    hipMemsetAsync(y1acc, 0, (size_t)B_SZ * HID * sizeof(float), stream);
    prep_kernel<<<dim3(1024), dim3(256), 0, stream>>>(img, tab, tbt, xhT, tc,
                                                      W1, wrowT);
    if (ws_size >= need) {
        gemm_fused<<<dim3(2048), dim3(512), 0, stream>>>(W1, tbt, xhT, tc, y1acc);
        tailmlp_kernel<<<dim3(256), dim3(128), 0, stream>>>(
            img, tab, wrowT, y1acc, b1, W2, b2, W3, b3, out);
    } else {
        gemm_fused_fb<<<dim3(2052), dim3(512), 0, stream>>>(W1, tbt, xhT, tc, y1acc);
        mlp_kernel<<<dim3(1024), dim3(128), 0, stream>>>(y1acc, b1, W2, b2, W3, b3, out);
    }
}